// Round 1
// baseline (2261.644 us; speedup 1.0000x reference)
//
#include <hip/hip_runtime.h>
#include <hip/hip_bf16.h>

// RGCN: out = hetero(relu(hetero(x, W1,b1)), W2,b2)
// hetero(x) = sum_r [ Din_r^-1/2 * A_r_selfloop * Dout_r^-1/2 * (x @ W_r) ] + sum_r b_r
// (row-scaling commutes with @W, so Y_r = x@W_r computed unscaled; norms folded
//  into per-edge coefficients during CSR aggregation)

constexpr int N   = 50000;
constexpr int R   = 3;
constexpr int IN  = 128;
constexpr int HID = 128;
constexpr int OUT = 64;
constexpr int M   = R * N;   // per-(relation,node) slots

// ---- bias sums: bsum1[j] = sum_r b1[r][j], bsum2 likewise ----
__global__ void bsum_kernel(const float* __restrict__ b1, const float* __restrict__ b2,
                            float* __restrict__ bsum1, float* __restrict__ bsum2) {
    int t = threadIdx.x;
    if (t < HID) bsum1[t] = b1[t] + b1[HID + t] + b1[2 * HID + t];
    if (t < OUT) bsum2[t] = b2[t] + b2[OUT + t] + b2[2 * OUT + t];
}

// ---- degree histograms (real edges only; +1 self-loop added later) ----
__global__ void count_kernel(const int* __restrict__ src, const int* __restrict__ dst, int E,
                             int* __restrict__ cin, int* __restrict__ cout_) {
    int g = blockIdx.x * 256 + threadIdx.x;
    if (g >= R * E) return;
    int r = g / E;
    atomicAdd(&cin[r * N + dst[g]], 1);
    atomicAdd(&cout_[r * N + src[g]], 1);
}

__global__ void rs_kernel(const int* __restrict__ cin, const int* __restrict__ cout_,
                          float* __restrict__ rs_in, float* __restrict__ rs_out) {
    int i = blockIdx.x * 256 + threadIdx.x;
    if (i >= M) return;
    rs_in[i]  = rsqrtf((float)(cin[i] + 1));   // self-loop adds 1 to every degree
    rs_out[i] = rsqrtf((float)(cout_[i] + 1));
}

// ---- single-block exclusive scan over M in-degree counts -> row_ptr, cursor ----
__global__ void scan_kernel(const int* __restrict__ cnt, int* __restrict__ row_ptr,
                            int* __restrict__ cursor) {
    __shared__ int lds[1024];
    int t = threadIdx.x;
    const int C = (M + 1023) / 1024;
    int lo = t * C, hi = lo + C; if (hi > M) hi = M; if (lo > M) lo = M;
    int s = 0;
    for (int i = lo; i < hi; i++) s += cnt[i];
    lds[t] = s;
    __syncthreads();
    for (int off = 1; off < 1024; off <<= 1) {
        int v = 0;
        if (t >= off) v = lds[t - off];
        __syncthreads();
        lds[t] += v;
        __syncthreads();
    }
    int base = (t == 0) ? 0 : lds[t - 1];
    for (int i = lo; i < hi; i++) { row_ptr[i] = base; cursor[i] = base; base += cnt[i]; }
    if (t == 1023) row_ptr[M] = lds[1023];
}

__global__ void fill_kernel(const int* __restrict__ src, const int* __restrict__ dst, int E,
                            int* __restrict__ cursor, int* __restrict__ esrc) {
    int g = blockIdx.x * 256 + threadIdx.x;
    if (g >= R * E) return;
    int r = g / E;
    int pos = atomicAdd(&cursor[r * N + dst[g]], 1);
    esrc[pos] = src[g];
}

// ---- broadcast a row-vector (bias sum) into every row of a buffer ----
__global__ void init_rows_kernel(float* __restrict__ dstbuf, const float* __restrict__ bvec,
                                 int total4, int mask4) {
    int i = blockIdx.x * 256 + threadIdx.x;
    if (i >= total4) return;
    ((float4*)dstbuf)[i] = ((const float4*)bvec)[i & mask4];
}

// ---- fp32 GEMM: Y[N,NOUT] = X[N,128] @ W[128,NOUT]; optional relu on X load ----
template <int NOUT, bool RELU>
__global__ __launch_bounds__(256) void gemm_kernel(const float* __restrict__ X,
                                                   const float* __restrict__ W,
                                                   float* __restrict__ Y) {
    constexpr int CG  = NOUT / 4;  // float4 col groups
    constexpr int RPT = CG / 8;    // rows per thread (NOUT=128 -> 4, NOUT=64 -> 2)
    __shared__ float sW[128 * NOUT];
    __shared__ float sX[32 * 128];
    int tid = threadIdx.x;
    int m0  = blockIdx.x * 32;

    const float4* W4 = (const float4*)W;
    float4* sW4 = (float4*)sW;
    for (int i = tid; i < 128 * NOUT / 4; i += 256) sW4[i] = W4[i];

    const float4* X4 = (const float4*)X;
    float4* sX4 = (float4*)sX;
    for (int i = tid; i < 32 * 32; i += 256) {
        int row = m0 + (i >> 5);
        float4 v = make_float4(0.f, 0.f, 0.f, 0.f);
        if (row < N) v = X4[(long)row * 32 + (i & 31)];
        if (RELU) {
            v.x = fmaxf(v.x, 0.f); v.y = fmaxf(v.y, 0.f);
            v.z = fmaxf(v.z, 0.f); v.w = fmaxf(v.w, 0.f);
        }
        sX4[i] = v;
    }
    __syncthreads();

    int cg   = tid % CG;
    int row0 = (tid / CG) * RPT;
    float4 acc[RPT];
#pragma unroll
    for (int i = 0; i < RPT; i++) acc[i] = make_float4(0.f, 0.f, 0.f, 0.f);

    for (int k = 0; k < 128; k += 4) {
        float4 w0 = sW4[(k + 0) * CG + cg];
        float4 w1 = sW4[(k + 1) * CG + cg];
        float4 w2 = sW4[(k + 2) * CG + cg];
        float4 w3 = sW4[(k + 3) * CG + cg];
#pragma unroll
        for (int i = 0; i < RPT; i++) {
            float4 xv = sX4[(row0 + i) * 32 + (k >> 2)];
            acc[i].x += xv.x * w0.x + xv.y * w1.x + xv.z * w2.x + xv.w * w3.x;
            acc[i].y += xv.x * w0.y + xv.y * w1.y + xv.z * w2.y + xv.w * w3.y;
            acc[i].z += xv.x * w0.z + xv.y * w1.z + xv.z * w2.z + xv.w * w3.z;
            acc[i].w += xv.x * w0.w + xv.y * w1.w + xv.z * w2.w + xv.w * w3.w;
        }
    }
#pragma unroll
    for (int i = 0; i < RPT; i++) {
        int row = m0 + row0 + i;
        if (row < N) ((float4*)Y)[(long)row * CG + cg] = acc[i];
    }
}

// ---- CSR aggregation, one wave per node, D=128 (float2/lane), accumulate into dest ----
__global__ __launch_bounds__(256) void agg128_kernel(const float* __restrict__ Y,
                                                     const float* __restrict__ rs_out,
                                                     const float* __restrict__ rs_in,
                                                     const int* __restrict__ row_ptr,
                                                     const int* __restrict__ esrc,
                                                     float* __restrict__ dest, int rbase) {
    int n = blockIdx.x * 4 + (threadIdx.x >> 6);
    if (n >= N) return;
    int lane = threadIdx.x & 63;
    const float2* Y2 = (const float2*)Y;
    float px = 0.f, py = 0.f;
    int beg = row_ptr[rbase + n], end = row_ptr[rbase + n + 1];
    for (int e = beg; e < end; e++) {
        int s = esrc[e];
        float c = rs_out[rbase + s];
        float2 y = Y2[(long)s * 64 + lane];
        px += c * y.x; py += c * y.y;
    }
    { // self-loop
        float c = rs_out[rbase + n];
        float2 y = Y2[(long)n * 64 + lane];
        px += c * y.x; py += c * y.y;
    }
    float ri = rs_in[rbase + n];
    float2* D2 = (float2*)dest;
    float2 d = D2[(long)n * 64 + lane];
    d.x += ri * px; d.y += ri * py;
    D2[(long)n * 64 + lane] = d;
}

// ---- same, D=64 (1 float/lane) ----
__global__ __launch_bounds__(256) void agg64_kernel(const float* __restrict__ Y,
                                                    const float* __restrict__ rs_out,
                                                    const float* __restrict__ rs_in,
                                                    const int* __restrict__ row_ptr,
                                                    const int* __restrict__ esrc,
                                                    float* __restrict__ dest, int rbase) {
    int n = blockIdx.x * 4 + (threadIdx.x >> 6);
    if (n >= N) return;
    int lane = threadIdx.x & 63;
    float p = 0.f;
    int beg = row_ptr[rbase + n], end = row_ptr[rbase + n + 1];
    for (int e = beg; e < end; e++) {
        int s = esrc[e];
        p += rs_out[rbase + s] * Y[(long)s * 64 + lane];
    }
    p += rs_out[rbase + n] * Y[(long)n * 64 + lane];
    dest[(long)n * 64 + lane] += rs_in[rbase + n] * p;
}

extern "C" void kernel_launch(void* const* d_in, const int* in_sizes, int n_in,
                              void* d_out, int out_size, void* d_ws, size_t ws_size,
                              hipStream_t stream) {
    const float* x  = (const float*)d_in[0];
    const int*  src = (const int*)d_in[1];
    const int*  dst = (const int*)d_in[2];
    const float* W1 = (const float*)d_in[3];
    const float* b1 = (const float*)d_in[4];
    const float* W2 = (const float*)d_in[5];
    const float* b2 = (const float*)d_in[6];
    float* out = (float*)d_out;
    const int E = in_sizes[1] / R;

    char* ws = (char*)d_ws;
    size_t off = 0;
    auto alloc = [&](size_t bytes) -> void* {
        void* p = ws + off;
        off += (bytes + 255) & ~(size_t)255;
        return p;
    };
    float* bsum1   = (float*)alloc(HID * 4);
    float* bsum2   = (float*)alloc(OUT * 4);
    float* rs_in   = (float*)alloc((size_t)M * 4);
    float* rs_out  = (float*)alloc((size_t)M * 4);
    int*   cin     = (int*)alloc((size_t)M * 4);
    int*   cout_   = (int*)alloc((size_t)M * 4);  // reused as cursor after rs_kernel
    int*   row_ptr = (int*)alloc((size_t)(M + 1) * 4);
    int*   esrc    = (int*)alloc((size_t)R * E * 4);
    float* Y       = (float*)alloc((size_t)N * HID * 4);  // per-relation X@W (reused)
    float* H       = (float*)alloc((size_t)N * HID * 4);  // layer-1 output (pre-relu)

    hipMemsetAsync(cin, 0, (size_t)M * 4, stream);
    hipMemsetAsync(cout_, 0, (size_t)M * 4, stream);

    bsum_kernel<<<1, 128, 0, stream>>>(b1, b2, bsum1, bsum2);
    const int eb = (R * E + 255) / 256;
    count_kernel<<<eb, 256, 0, stream>>>(src, dst, E, cin, cout_);
    rs_kernel<<<(M + 255) / 256, 256, 0, stream>>>(cin, cout_, rs_in, rs_out);
    scan_kernel<<<1, 1024, 0, stream>>>(cin, row_ptr, cout_);
    fill_kernel<<<eb, 256, 0, stream>>>(src, dst, E, cout_, esrc);

    const int gb = (N + 31) / 32;
    const int ab = (N + 3) / 4;

    // layer 1: H = bsum1 + sum_r Din^-1/2 A_r Dout^-1/2 (x @ W1_r)
    init_rows_kernel<<<(N * HID / 4 + 255) / 256, 256, 0, stream>>>(H, bsum1, N * HID / 4, 31);
    for (int r = 0; r < R; r++) {
        gemm_kernel<128, false><<<gb, 256, 0, stream>>>(x, W1 + (size_t)r * IN * HID, Y);
        agg128_kernel<<<ab, 256, 0, stream>>>(Y, rs_out, rs_in, row_ptr, esrc, H, r * N);
    }
    // layer 2: out = bsum2 + sum_r Din^-1/2 A_r Dout^-1/2 (relu(H) @ W2_r)
    init_rows_kernel<<<(N * OUT / 4 + 255) / 256, 256, 0, stream>>>(out, bsum2, N * OUT / 4, 15);
    for (int r = 0; r < R; r++) {
        gemm_kernel<64, true><<<gb, 256, 0, stream>>>(H, W2 + (size_t)r * HID * OUT, Y);
        agg64_kernel<<<ab, 256, 0, stream>>>(Y, rs_out, rs_in, row_ptr, esrc, out, r * N);
    }
}

// Round 2
// 1175.346 us; speedup vs baseline: 1.9242x; 1.9242x over previous
//
#include <hip/hip_runtime.h>
#include <hip/hip_bf16.h>

// RGCN: out = hetero(relu(hetero(x, W1,b1)), W2,b2)
// hetero(x) = sum_r [ Din_r^-1/2 * A_r_selfloop * Dout_r^-1/2 * (x @ W_r) ] + sum_r b_r
// Row-scaling commutes with @W: Y_r = (x@W_r) scaled by rs_out in the GEMM
// epilogue; rs_in applied in the aggregation epilogue. CSR-by-dst aggregation,
// one wave per node (deterministic, no fp32 atomics).

constexpr int N   = 50000;
constexpr int R   = 3;
constexpr int IN  = 128;
constexpr int HID = 128;
constexpr int OUT = 64;
constexpr int M   = R * N;   // per-(relation,node) slots
constexpr int NB_SCAN = (M + 1023) / 1024;  // 147 scan blocks

// ---- bias sums: bsum1[j] = sum_r b1[r][j], bsum2 likewise ----
__global__ void bsum_kernel(const float* __restrict__ b1, const float* __restrict__ b2,
                            float* __restrict__ bsum1, float* __restrict__ bsum2) {
    int t = threadIdx.x;
    if (t < HID) bsum1[t] = b1[t] + b1[HID + t] + b1[2 * HID + t];
    if (t < OUT) bsum2[t] = b2[t] + b2[OUT + t] + b2[2 * OUT + t];
}

// ---- degree histograms (real edges only; +1 self-loop added later) ----
__global__ void count_kernel(const int* __restrict__ src, const int* __restrict__ dst, int E,
                             int* __restrict__ cin, int* __restrict__ cout_) {
    int g = blockIdx.x * 256 + threadIdx.x;
    if (g >= R * E) return;
    int r = g / E;
    atomicAdd(&cin[r * N + dst[g]], 1);
    atomicAdd(&cout_[r * N + src[g]], 1);
}

__global__ void rs_kernel(const int* __restrict__ cin, const int* __restrict__ cout_,
                          float* __restrict__ rs_in, float* __restrict__ rs_out) {
    int i = blockIdx.x * 256 + threadIdx.x;
    if (i >= M) return;
    rs_in[i]  = rsqrtf((float)(cin[i] + 1));   // self-loop adds 1 to every degree
    rs_out[i] = rsqrtf((float)(cout_[i] + 1));
}

// ---- hierarchical exclusive scan over M in-degree counts -> row_ptr, cursor ----
// stage 1: per-block (1024 elems) scan; write within-block exclusive + block total
__global__ void scan1_kernel(const int* __restrict__ cnt, int* __restrict__ row_ptr,
                             int* __restrict__ partials) {
    __shared__ int lds[1024];
    int t = threadIdx.x;
    int idx = blockIdx.x * 1024 + t;
    int v = (idx < M) ? cnt[idx] : 0;
    lds[t] = v;
    __syncthreads();
    for (int off = 1; off < 1024; off <<= 1) {
        int u = (t >= off) ? lds[t - off] : 0;
        __syncthreads();
        lds[t] += u;
        __syncthreads();
    }
    if (idx < M) row_ptr[idx] = lds[t] - v;     // exclusive within block
    if (t == 1023) partials[blockIdx.x] = lds[1023];
}

// stage 2: single tiny block scans the 147 block totals in place (-> exclusive offsets)
__global__ void scan2_kernel(int* __restrict__ partials, int* __restrict__ row_ptr, int nb) {
    __shared__ int lds[256];
    int t = threadIdx.x;
    int v = (t < nb) ? partials[t] : 0;
    lds[t] = v;
    __syncthreads();
    for (int off = 1; off < 256; off <<= 1) {
        int u = (t >= off) ? lds[t - off] : 0;
        __syncthreads();
        lds[t] += u;
        __syncthreads();
    }
    if (t < nb) partials[t] = lds[t] - v;       // exclusive block offset
    if (t == 255) row_ptr[M] = lds[255];        // grand total
}

// stage 3: add block offsets; init cursor
__global__ void scan3_kernel(int* __restrict__ row_ptr, int* __restrict__ cursor,
                             const int* __restrict__ partials) {
    int i = blockIdx.x * 256 + threadIdx.x;
    if (i >= M) return;
    int v = row_ptr[i] + partials[i >> 10];
    row_ptr[i] = v;
    cursor[i] = v;
}

__global__ void fill_kernel(const int* __restrict__ src, const int* __restrict__ dst, int E,
                            int* __restrict__ cursor, int* __restrict__ esrc) {
    int g = blockIdx.x * 256 + threadIdx.x;
    if (g >= R * E) return;
    int r = g / E;
    int pos = atomicAdd(&cursor[r * N + dst[g]], 1);
    esrc[pos] = src[g];
}

// ---- broadcast a row-vector (bias sum) into every row of a buffer ----
__global__ void init_rows_kernel(float* __restrict__ dstbuf, const float* __restrict__ bvec,
                                 int total4, int mask4) {
    int i = blockIdx.x * 256 + threadIdx.x;
    if (i >= total4) return;
    ((float4*)dstbuf)[i] = ((const float4*)bvec)[i & mask4];
}

// ---- fp32 GEMM: Y[N,WC] = (relu?)X[N,128] @ Wr[128,WC], epilogue *= rs_out_r[row]
// 64-row x 64-col tile per block; full K=128 staged in LDS; X padded to stride 132.
template <int WC, bool RELU>
__global__ __launch_bounds__(256) void gemm_kernel(const float* __restrict__ X,
                                                   const float* __restrict__ Wr,
                                                   const float* __restrict__ rs_out_r,
                                                   float* __restrict__ Y) {
    __shared__ float sX[64 * 132];   // 64 rows x 128 K, +4 pad
    __shared__ float sW[128 * 64];   // 128 K x 64 cols
    int tid = threadIdx.x;
    int m0  = blockIdx.x * 64;
    int c0  = blockIdx.y * 64;

    const float4* X4 = (const float4*)X;
    for (int j = tid; j < 64 * 32; j += 256) {
        int row = j >> 5, c4 = j & 31;
        float4 v = make_float4(0.f, 0.f, 0.f, 0.f);
        if (m0 + row < N) v = X4[(long)(m0 + row) * 32 + c4];
        if (RELU) {
            v.x = fmaxf(v.x, 0.f); v.y = fmaxf(v.y, 0.f);
            v.z = fmaxf(v.z, 0.f); v.w = fmaxf(v.w, 0.f);
        }
        *(float4*)&sX[row * 132 + c4 * 4] = v;
    }
    const float* Wb = Wr + c0;
    for (int j = tid; j < 128 * 16; j += 256) {
        int k = j >> 4, c4 = j & 15;
        *(float4*)&sW[k * 64 + c4 * 4] = *(const float4*)&Wb[(long)k * WC + c4 * 4];
    }
    __syncthreads();

    int tx = tid & 15;   // 4 cols: c0 + tx*4
    int ty = tid >> 4;   // 4 rows: m0 + ty*4 ..
    float4 acc[4];
#pragma unroll
    for (int i = 0; i < 4; i++) acc[i] = make_float4(0.f, 0.f, 0.f, 0.f);

    for (int k = 0; k < 128; k += 4) {
        float4 w0 = *(float4*)&sW[(k + 0) * 64 + tx * 4];
        float4 w1 = *(float4*)&sW[(k + 1) * 64 + tx * 4];
        float4 w2 = *(float4*)&sW[(k + 2) * 64 + tx * 4];
        float4 w3 = *(float4*)&sW[(k + 3) * 64 + tx * 4];
#pragma unroll
        for (int i = 0; i < 4; i++) {
            float4 xv = *(float4*)&sX[(ty * 4 + i) * 132 + k];
            acc[i].x += xv.x * w0.x + xv.y * w1.x + xv.z * w2.x + xv.w * w3.x;
            acc[i].y += xv.x * w0.y + xv.y * w1.y + xv.z * w2.y + xv.w * w3.y;
            acc[i].z += xv.x * w0.z + xv.y * w1.z + xv.z * w2.z + xv.w * w3.z;
            acc[i].w += xv.x * w0.w + xv.y * w1.w + xv.z * w2.w + xv.w * w3.w;
        }
    }
#pragma unroll
    for (int i = 0; i < 4; i++) {
        int row = m0 + ty * 4 + i;
        if (row < N) {
            float s = rs_out_r[row];
            float4 a = acc[i];
            a.x *= s; a.y *= s; a.z *= s; a.w *= s;
            *(float4*)&Y[(long)row * WC + c0 + tx * 4] = a;
        }
    }
}

// ---- CSR aggregation, one wave per node, D=128 (float2/lane); Y pre-scaled by rs_out ----
__global__ __launch_bounds__(256) void agg128_kernel(const float* __restrict__ Y,
                                                     const float* __restrict__ rs_in,
                                                     const int* __restrict__ row_ptr,
                                                     const int* __restrict__ esrc,
                                                     float* __restrict__ dest, int rbase) {
    int n = blockIdx.x * 4 + (threadIdx.x >> 6);
    if (n >= N) return;
    int lane = threadIdx.x & 63;
    const float2* Y2 = (const float2*)Y;
    float px = 0.f, py = 0.f;
    int beg = row_ptr[rbase + n], end = row_ptr[rbase + n + 1];
    for (int e = beg; e < end; e++) {
        int s = esrc[e];
        float2 y = Y2[(long)s * 64 + lane];
        px += y.x; py += y.y;
    }
    { // self-loop (Y already carries rs_out)
        float2 y = Y2[(long)n * 64 + lane];
        px += y.x; py += y.y;
    }
    float ri = rs_in[rbase + n];
    float2* D2 = (float2*)dest;
    float2 d = D2[(long)n * 64 + lane];
    d.x += ri * px; d.y += ri * py;
    D2[(long)n * 64 + lane] = d;
}

// ---- same, D=64 (1 float/lane) ----
__global__ __launch_bounds__(256) void agg64_kernel(const float* __restrict__ Y,
                                                    const float* __restrict__ rs_in,
                                                    const int* __restrict__ row_ptr,
                                                    const int* __restrict__ esrc,
                                                    float* __restrict__ dest, int rbase) {
    int n = blockIdx.x * 4 + (threadIdx.x >> 6);
    if (n >= N) return;
    int lane = threadIdx.x & 63;
    float p = 0.f;
    int beg = row_ptr[rbase + n], end = row_ptr[rbase + n + 1];
    for (int e = beg; e < end; e++) {
        p += Y[(long)esrc[e] * 64 + lane];
    }
    p += Y[(long)n * 64 + lane];
    dest[(long)n * 64 + lane] += rs_in[rbase + n] * p;
}

extern "C" void kernel_launch(void* const* d_in, const int* in_sizes, int n_in,
                              void* d_out, int out_size, void* d_ws, size_t ws_size,
                              hipStream_t stream) {
    const float* x  = (const float*)d_in[0];
    const int*  src = (const int*)d_in[1];
    const int*  dst = (const int*)d_in[2];
    const float* W1 = (const float*)d_in[3];
    const float* b1 = (const float*)d_in[4];
    const float* W2 = (const float*)d_in[5];
    const float* b2 = (const float*)d_in[6];
    float* out = (float*)d_out;
    const int E = in_sizes[1] / R;

    char* ws = (char*)d_ws;
    size_t off = 0;
    auto alloc = [&](size_t bytes) -> void* {
        void* p = ws + off;
        off += (bytes + 255) & ~(size_t)255;
        return p;
    };
    float* bsum1    = (float*)alloc(HID * 4);
    float* bsum2    = (float*)alloc(OUT * 4);
    float* rs_in    = (float*)alloc((size_t)M * 4);
    float* rs_out   = (float*)alloc((size_t)M * 4);
    int*   cin      = (int*)alloc((size_t)M * 4);
    int*   cout_    = (int*)alloc((size_t)M * 4);
    int*   cursor   = (int*)alloc((size_t)M * 4);
    int*   row_ptr  = (int*)alloc((size_t)(M + 1) * 4);
    int*   partials = (int*)alloc((size_t)NB_SCAN * 4);
    int*   esrc     = (int*)alloc((size_t)R * E * 4);
    float* Y        = (float*)alloc((size_t)N * HID * 4);  // per-relation (x@W)*rs_out
    float* H        = (float*)alloc((size_t)N * HID * 4);  // layer-1 output

    hipMemsetAsync(cin, 0, (size_t)M * 4, stream);
    hipMemsetAsync(cout_, 0, (size_t)M * 4, stream);

    bsum_kernel<<<1, 128, 0, stream>>>(b1, b2, bsum1, bsum2);
    const int eb = (R * E + 255) / 256;
    count_kernel<<<eb, 256, 0, stream>>>(src, dst, E, cin, cout_);
    rs_kernel<<<(M + 255) / 256, 256, 0, stream>>>(cin, cout_, rs_in, rs_out);
    scan1_kernel<<<NB_SCAN, 1024, 0, stream>>>(cin, row_ptr, partials);
    scan2_kernel<<<1, 256, 0, stream>>>(partials, row_ptr, NB_SCAN);
    scan3_kernel<<<(M + 255) / 256, 256, 0, stream>>>(row_ptr, cursor, partials);
    fill_kernel<<<eb, 256, 0, stream>>>(src, dst, E, cursor, esrc);

    const int gb = (N + 63) / 64;   // 782
    const int ab = (N + 3) / 4;

    // layer 1: H = bsum1 + sum_r rs_in_r * A_sl_r * [rs_out_r * (x @ W1_r)]
    init_rows_kernel<<<(N * HID / 4 + 255) / 256, 256, 0, stream>>>(H, bsum1, N * HID / 4, 31);
    for (int r = 0; r < R; r++) {
        gemm_kernel<128, false><<<dim3(gb, 2), 256, 0, stream>>>(
            x, W1 + (size_t)r * IN * HID, rs_out + (size_t)r * N, Y);
        agg128_kernel<<<ab, 256, 0, stream>>>(Y, rs_in, row_ptr, esrc, H, r * N);
    }
    // layer 2: out = bsum2 + sum_r rs_in_r * A_sl_r * [rs_out_r * (relu(H) @ W2_r)]
    init_rows_kernel<<<(N * OUT / 4 + 255) / 256, 256, 0, stream>>>(out, bsum2, N * OUT / 4, 15);
    for (int r = 0; r < R; r++) {
        gemm_kernel<64, true><<<dim3(gb, 1), 256, 0, stream>>>(
            H, W2 + (size_t)r * HID * OUT, rs_out + (size_t)r * N, Y);
        agg64_kernel<<<ab, 256, 0, stream>>>(Y, rs_in, row_ptr, esrc, out, r * N);
    }
}

// Round 3
// 1072.590 us; speedup vs baseline: 2.1086x; 1.0958x over previous
//
#include <hip/hip_runtime.h>
#include <hip/hip_bf16.h>

// RGCN: out = hetero(relu(hetero(x, W1,b1)), W2,b2)
// hetero(x) = sum_r [ Din_r^-1/2 * A_r_selfloop * Dout_r^-1/2 * (x @ W_r) ] + sum_r b_r
// Row-scaling commutes with @W: rs_out folded into GEMM epilogue, rs_in into
// aggregation epilogue, bias folded into first relation's aggregation.
// CSR build is XCD-partitioned (blockIdx%8 -> dst-range) so cursor/esrc cache
// lines are owned by a single XCD L2 (kills the 17x write amplification seen
// in round 2: 163 MB WRITE for a 9.6 MB buffer).

constexpr int N   = 50000;
constexpr int R   = 3;
constexpr int IN  = 128;
constexpr int HID = 128;
constexpr int OUT = 64;
constexpr int M   = R * N;                   // per-(relation,node) slots
constexpr int NB_SCAN = (M + 1023) / 1024;   // 147 scan blocks
constexpr int PART = (N + 7) / 8;            // 6250 dst-nodes per XCD partition
constexpr int CHUNK = 16384;                 // edges per block chunk

// ---- bias sums: bsum1[j] = sum_r b1[r][j], bsum2 likewise ----
__global__ void bsum_kernel(const float* __restrict__ b1, const float* __restrict__ b2,
                            float* __restrict__ bsum1, float* __restrict__ bsum2) {
    int t = threadIdx.x;
    if (t < HID) bsum1[t] = b1[t] + b1[HID + t] + b1[2 * HID + t];
    if (t < OUT) bsum2[t] = b2[t] + b2[OUT + t] + b2[2 * OUT + t];
}

// ---- XCD-partitioned degree histograms (real edges; +1 self-loop later) ----
// block b: partition p=b&7 (node range), chunk c=b>>3 (edge range).
__global__ __launch_bounds__(256) void count_kernel(const int* __restrict__ src,
                                                    const int* __restrict__ dst,
                                                    int E, int RE,
                                                    int* __restrict__ cin,
                                                    int* __restrict__ cout_) {
    int p = blockIdx.x & 7;
    int lo = p * PART;
    int hi = min(N, lo + PART);
    int beg = (blockIdx.x >> 3) * CHUNK;
    int end = min(RE, beg + CHUNK);
    for (int g = beg + (int)threadIdx.x; g < end; g += 256) {
        int r = (g >= 2 * E) ? 2 : (g >= E) ? 1 : 0;
        int d = dst[g];
        if (d >= lo && d < hi) atomicAdd(&cin[r * N + d], 1);
        int s = src[g];
        if (s >= lo && s < hi) atomicAdd(&cout_[r * N + s], 1);
    }
}

__global__ void rs_kernel(const int* __restrict__ cin, const int* __restrict__ cout_,
                          float* __restrict__ rs_in, float* __restrict__ rs_out) {
    int i = blockIdx.x * 256 + threadIdx.x;
    if (i >= M) return;
    rs_in[i]  = rsqrtf((float)(cin[i] + 1));   // self-loop adds 1 to every degree
    rs_out[i] = rsqrtf((float)(cout_[i] + 1));
}

// ---- hierarchical exclusive scan over M in-degree counts -> row_ptr, cursor ----
__global__ void scan1_kernel(const int* __restrict__ cnt, int* __restrict__ row_ptr,
                             int* __restrict__ partials) {
    __shared__ int lds[1024];
    int t = threadIdx.x;
    int idx = blockIdx.x * 1024 + t;
    int v = (idx < M) ? cnt[idx] : 0;
    lds[t] = v;
    __syncthreads();
    for (int off = 1; off < 1024; off <<= 1) {
        int u = (t >= off) ? lds[t - off] : 0;
        __syncthreads();
        lds[t] += u;
        __syncthreads();
    }
    if (idx < M) row_ptr[idx] = lds[t] - v;     // exclusive within block
    if (t == 1023) partials[blockIdx.x] = lds[1023];
}

__global__ void scan2_kernel(int* __restrict__ partials, int* __restrict__ row_ptr, int nb) {
    __shared__ int lds[256];
    int t = threadIdx.x;
    int v = (t < nb) ? partials[t] : 0;
    lds[t] = v;
    __syncthreads();
    for (int off = 1; off < 256; off <<= 1) {
        int u = (t >= off) ? lds[t - off] : 0;
        __syncthreads();
        lds[t] += u;
        __syncthreads();
    }
    if (t < nb) partials[t] = lds[t] - v;       // exclusive block offset
    if (t == 255) row_ptr[M] = lds[255];        // grand total
}

__global__ void scan3_kernel(int* __restrict__ row_ptr, int* __restrict__ cursor,
                             const int* __restrict__ partials) {
    int i = blockIdx.x * 256 + threadIdx.x;
    if (i >= M) return;
    int v = row_ptr[i] + partials[i >> 10];
    row_ptr[i] = v;
    cursor[i] = v;
}

// ---- XCD-partitioned CSR fill: only the owning partition writes a dst's slots ----
__global__ __launch_bounds__(256) void fill_kernel(const int* __restrict__ src,
                                                   const int* __restrict__ dst,
                                                   int E, int RE,
                                                   int* __restrict__ cursor,
                                                   int* __restrict__ esrc) {
    int p = blockIdx.x & 7;
    int lo = p * PART;
    int hi = min(N, lo + PART);
    int beg = (blockIdx.x >> 3) * CHUNK;
    int end = min(RE, beg + CHUNK);
    for (int g = beg + (int)threadIdx.x; g < end; g += 256) {
        int d = dst[g];
        if (d >= lo && d < hi) {
            int r = (g >= 2 * E) ? 2 : (g >= E) ? 1 : 0;
            int pos = atomicAdd(&cursor[r * N + d], 1);
            esrc[pos] = src[g];
        }
    }
}

// ---- fp32 GEMM: Y[N,WC] = (relu?)X[N,128] @ Wr[128,WC], epilogue *= rs_out_r[row]
template <int WC, bool RELU>
__global__ __launch_bounds__(256) void gemm_kernel(const float* __restrict__ X,
                                                   const float* __restrict__ Wr,
                                                   const float* __restrict__ rs_out_r,
                                                   float* __restrict__ Y) {
    __shared__ float sX[64 * 132];   // 64 rows x 128 K, +4 pad
    __shared__ float sW[128 * 64];   // 128 K x 64 cols
    int tid = threadIdx.x;
    int m0  = blockIdx.x * 64;
    int c0  = blockIdx.y * 64;

    const float4* X4 = (const float4*)X;
    for (int j = tid; j < 64 * 32; j += 256) {
        int row = j >> 5, c4 = j & 31;
        float4 v = make_float4(0.f, 0.f, 0.f, 0.f);
        if (m0 + row < N) v = X4[(long)(m0 + row) * 32 + c4];
        if (RELU) {
            v.x = fmaxf(v.x, 0.f); v.y = fmaxf(v.y, 0.f);
            v.z = fmaxf(v.z, 0.f); v.w = fmaxf(v.w, 0.f);
        }
        *(float4*)&sX[row * 132 + c4 * 4] = v;
    }
    const float* Wb = Wr + c0;
    for (int j = tid; j < 128 * 16; j += 256) {
        int k = j >> 4, c4 = j & 15;
        *(float4*)&sW[k * 64 + c4 * 4] = *(const float4*)&Wb[(long)k * WC + c4 * 4];
    }
    __syncthreads();

    int tx = tid & 15;   // 4 cols: c0 + tx*4
    int ty = tid >> 4;   // 4 rows
    float4 acc[4];
#pragma unroll
    for (int i = 0; i < 4; i++) acc[i] = make_float4(0.f, 0.f, 0.f, 0.f);

    for (int k = 0; k < 128; k += 4) {
        float4 w0 = *(float4*)&sW[(k + 0) * 64 + tx * 4];
        float4 w1 = *(float4*)&sW[(k + 1) * 64 + tx * 4];
        float4 w2 = *(float4*)&sW[(k + 2) * 64 + tx * 4];
        float4 w3 = *(float4*)&sW[(k + 3) * 64 + tx * 4];
#pragma unroll
        for (int i = 0; i < 4; i++) {
            float4 xv = *(float4*)&sX[(ty * 4 + i) * 132 + k];
            acc[i].x += xv.x * w0.x + xv.y * w1.x + xv.z * w2.x + xv.w * w3.x;
            acc[i].y += xv.x * w0.y + xv.y * w1.y + xv.z * w2.y + xv.w * w3.y;
            acc[i].z += xv.x * w0.z + xv.y * w1.z + xv.z * w2.z + xv.w * w3.z;
            acc[i].w += xv.x * w0.w + xv.y * w1.w + xv.z * w2.w + xv.w * w3.w;
        }
    }
#pragma unroll
    for (int i = 0; i < 4; i++) {
        int row = m0 + ty * 4 + i;
        if (row < N) {
            float s = rs_out_r[row];
            float4 a = acc[i];
            a.x *= s; a.y *= s; a.z *= s; a.w *= s;
            *(float4*)&Y[(long)row * WC + c0 + tx * 4] = a;
        }
    }
}

// ---- CSR aggregation, one wave per node, D=128 (float2/lane); Y pre-scaled by
// rs_out; FIRST relation initializes accumulator from the bias sum. ----
template <bool FIRST>
__global__ __launch_bounds__(256) void agg128_kernel(const float* __restrict__ Y,
                                                     const float* __restrict__ rs_in,
                                                     const int* __restrict__ row_ptr,
                                                     const int* __restrict__ esrc,
                                                     const float* __restrict__ bias,
                                                     float* __restrict__ dest, int rbase) {
    int n = blockIdx.x * 4 + (threadIdx.x >> 6);
    if (n >= N) return;
    int lane = threadIdx.x & 63;
    const float2* Y2 = (const float2*)Y;
    float px = 0.f, py = 0.f;
    int beg = row_ptr[rbase + n], end = row_ptr[rbase + n + 1];
    for (int e = beg; e < end; e++) {
        float2 y = Y2[(long)esrc[e] * 64 + lane];
        px += y.x; py += y.y;
    }
    { // self-loop (Y already carries rs_out)
        float2 y = Y2[(long)n * 64 + lane];
        px += y.x; py += y.y;
    }
    float ri = rs_in[rbase + n];
    float2* D2 = (float2*)dest;
    float2 d = FIRST ? ((const float2*)bias)[lane] : D2[(long)n * 64 + lane];
    d.x += ri * px; d.y += ri * py;
    D2[(long)n * 64 + lane] = d;
}

// ---- same, D=64 (1 float/lane) ----
template <bool FIRST>
__global__ __launch_bounds__(256) void agg64_kernel(const float* __restrict__ Y,
                                                    const float* __restrict__ rs_in,
                                                    const int* __restrict__ row_ptr,
                                                    const int* __restrict__ esrc,
                                                    const float* __restrict__ bias,
                                                    float* __restrict__ dest, int rbase) {
    int n = blockIdx.x * 4 + (threadIdx.x >> 6);
    if (n >= N) return;
    int lane = threadIdx.x & 63;
    float p = 0.f;
    int beg = row_ptr[rbase + n], end = row_ptr[rbase + n + 1];
    for (int e = beg; e < end; e++) {
        p += Y[(long)esrc[e] * 64 + lane];
    }
    p += Y[(long)n * 64 + lane];
    float d = FIRST ? bias[lane] : dest[(long)n * 64 + lane];
    dest[(long)n * 64 + lane] = d + rs_in[rbase + n] * p;
}

extern "C" void kernel_launch(void* const* d_in, const int* in_sizes, int n_in,
                              void* d_out, int out_size, void* d_ws, size_t ws_size,
                              hipStream_t stream) {
    const float* x  = (const float*)d_in[0];
    const int*  src = (const int*)d_in[1];
    const int*  dst = (const int*)d_in[2];
    const float* W1 = (const float*)d_in[3];
    const float* b1 = (const float*)d_in[4];
    const float* W2 = (const float*)d_in[5];
    const float* b2 = (const float*)d_in[6];
    float* out = (float*)d_out;
    const int E  = in_sizes[1] / R;
    const int RE = in_sizes[1];

    char* ws = (char*)d_ws;
    size_t off = 0;
    auto alloc = [&](size_t bytes) -> void* {
        void* p = ws + off;
        off += (bytes + 255) & ~(size_t)255;
        return p;
    };
    float* bsum1    = (float*)alloc(HID * 4);
    float* bsum2    = (float*)alloc(OUT * 4);
    float* rs_in    = (float*)alloc((size_t)M * 4);
    float* rs_out   = (float*)alloc((size_t)M * 4);
    int*   cin      = (int*)alloc((size_t)M * 4);
    int*   cout_    = (int*)alloc((size_t)M * 4);
    int*   cursor   = (int*)alloc((size_t)M * 4);
    int*   row_ptr  = (int*)alloc((size_t)(M + 1) * 4);
    int*   partials = (int*)alloc((size_t)NB_SCAN * 4);
    int*   esrc     = (int*)alloc((size_t)RE * 4);
    float* Y        = (float*)alloc((size_t)N * HID * 4);  // per-relation (x@W)*rs_out
    float* H        = (float*)alloc((size_t)N * HID * 4);  // layer-1 output

    hipMemsetAsync(cin, 0, (size_t)M * 4, stream);
    hipMemsetAsync(cout_, 0, (size_t)M * 4, stream);

    bsum_kernel<<<1, 128, 0, stream>>>(b1, b2, bsum1, bsum2);
    const int nchunk = (RE + CHUNK - 1) / CHUNK;
    count_kernel<<<nchunk * 8, 256, 0, stream>>>(src, dst, E, RE, cin, cout_);
    rs_kernel<<<(M + 255) / 256, 256, 0, stream>>>(cin, cout_, rs_in, rs_out);
    scan1_kernel<<<NB_SCAN, 1024, 0, stream>>>(cin, row_ptr, partials);
    scan2_kernel<<<1, 256, 0, stream>>>(partials, row_ptr, NB_SCAN);
    scan3_kernel<<<(M + 255) / 256, 256, 0, stream>>>(row_ptr, cursor, partials);
    fill_kernel<<<nchunk * 8, 256, 0, stream>>>(src, dst, E, RE, cursor, esrc);

    const int gb = (N + 63) / 64;   // 782
    const int ab = (N + 3) / 4;

    // layer 1: H = bsum1 + sum_r rs_in_r * A_sl_r * [rs_out_r * (x @ W1_r)]
    for (int r = 0; r < R; r++) {
        gemm_kernel<128, false><<<dim3(gb, 2), 256, 0, stream>>>(
            x, W1 + (size_t)r * IN * HID, rs_out + (size_t)r * N, Y);
        if (r == 0)
            agg128_kernel<true><<<ab, 256, 0, stream>>>(Y, rs_in, row_ptr, esrc, bsum1, H, r * N);
        else
            agg128_kernel<false><<<ab, 256, 0, stream>>>(Y, rs_in, row_ptr, esrc, bsum1, H, r * N);
    }
    // layer 2: out = bsum2 + sum_r rs_in_r * A_sl_r * [rs_out_r * (relu(H) @ W2_r)]
    for (int r = 0; r < R; r++) {
        gemm_kernel<64, true><<<dim3(gb, 1), 256, 0, stream>>>(
            H, W2 + (size_t)r * HID * OUT, rs_out + (size_t)r * N, Y);
        if (r == 0)
            agg64_kernel<true><<<ab, 256, 0, stream>>>(Y, rs_in, row_ptr, esrc, bsum2, out, r * N);
        else
            agg64_kernel<false><<<ab, 256, 0, stream>>>(Y, rs_in, row_ptr, esrc, bsum2, out, r * N);
    }
}

// Round 4
// 650.187 us; speedup vs baseline: 3.4785x; 1.6497x over previous
//
#include <hip/hip_runtime.h>
#include <hip/hip_bf16.h>

// RGCN: out = hetero(relu(hetero(x, W1,b1)), W2,b2)
// hetero(x) = sum_r [ Din_r^-1/2 * A_r_selfloop * Dout_r^-1/2 * (x @ W_r) ] + sum_r b_r
// rs_out folded into GEMM epilogue, rs_in + bias folded into aggregation.
// CSR build is a two-pass radix partition with ZERO global atomics (round-3
// lesson: every device-scope atomicAdd costs ~32B of fabric write traffic —
// 4.8M atomics = 149MB WRITE_SIZE; LDS atomics are free).

constexpr int N   = 50000;
constexpr int R   = 3;
constexpr int IN  = 128;
constexpr int HID = 128;
constexpr int OUT = 64;
constexpr int M   = R * N;                 // 150000 (rel,node) slots
constexpr int BK  = 1024;                  // keys per bucket
constexpr int NBKT = (M + BK - 1) / BK;    // 147 buckets
constexpr int CHUNK = 8192;                // edges per partition block

// ---- bias sums: bsum1[j] = sum_r b1[r][j], bsum2 likewise ----
__global__ void bsum_kernel(const float* __restrict__ b1, const float* __restrict__ b2,
                            float* __restrict__ bsum1, float* __restrict__ bsum2) {
    int t = threadIdx.x;
    if (t < HID) bsum1[t] = b1[t] + b1[HID + t] + b1[2 * HID + t];
    if (t < OUT) bsum2[t] = b2[t] + b2[OUT + t] + b2[2 * OUT + t];
}

// ---- P1: coarse bucket histograms per edge-chunk (dst-keyed and src-keyed) ----
__global__ __launch_bounds__(256) void p1_kernel(const int* __restrict__ src,
                                                 const int* __restrict__ dst,
                                                 int E, int RE, int nb,
                                                 int* __restrict__ bh) {
    __shared__ int hd[NBKT], hs[NBKT];
    for (int i = threadIdx.x; i < NBKT; i += 256) { hd[i] = 0; hs[i] = 0; }
    __syncthreads();
    int beg = blockIdx.x * CHUNK, end = min(RE, beg + CHUNK);
    for (int g = beg + (int)threadIdx.x; g < end; g += 256) {
        int rb = ((g >= E) + (g >= 2 * E)) * N;
        atomicAdd(&hd[(rb + dst[g]) >> 10], 1);
        atomicAdd(&hs[(rb + src[g]) >> 10], 1);
    }
    __syncthreads();
    for (int i = threadIdx.x; i < NBKT; i += 256) {
        bh[i * nb + blockIdx.x] = hd[i];                 // [bucket][block], d-half
        bh[(NBKT + i) * nb + blockIdx.x] = hs[i];        // s-half
    }
}

// ---- generic 3-stage exclusive scan over L ints ----
__global__ void scan1_kernel(const int* __restrict__ in, int* __restrict__ out,
                             int* __restrict__ partials, int L) {
    __shared__ int lds[1024];
    int t = threadIdx.x;
    int idx = blockIdx.x * 1024 + t;
    int v = (idx < L) ? in[idx] : 0;
    lds[t] = v;
    __syncthreads();
    for (int off = 1; off < 1024; off <<= 1) {
        int u = (t >= off) ? lds[t - off] : 0;
        __syncthreads();
        lds[t] += u;
        __syncthreads();
    }
    if (idx < L) out[idx] = lds[t] - v;
    if (t == 1023) partials[blockIdx.x] = lds[1023];
}

__global__ void scan2_kernel(int* __restrict__ partials, int nb1) {
    __shared__ int lds[256];
    int t = threadIdx.x;
    int v = (t < nb1) ? partials[t] : 0;
    lds[t] = v;
    __syncthreads();
    for (int off = 1; off < 256; off <<= 1) {
        int u = (t >= off) ? lds[t - off] : 0;
        __syncthreads();
        lds[t] += u;
        __syncthreads();
    }
    if (t < nb1) partials[t] = lds[t] - v;
}

__global__ void scan3_kernel(int* __restrict__ out, const int* __restrict__ partials, int L) {
    int i = blockIdx.x * 256 + threadIdx.x;
    if (i < L) out[i] += partials[i >> 10];
}

// ---- P3: scatter edges into bucket-sorted buffers via LDS cursors ----
// ebd[pos] = (src<<10)|(key&1023)  (src<65536 so pack fits 26 bits)
// ebs[pos] = key&1023
__global__ __launch_bounds__(256) void p3_kernel(const int* __restrict__ src,
                                                 const int* __restrict__ dst,
                                                 int E, int RE, int nb,
                                                 const int* __restrict__ scanv,
                                                 int* __restrict__ ebd,
                                                 int* __restrict__ ebs) {
    __shared__ int cd[NBKT], cs[NBKT];
    for (int i = threadIdx.x; i < NBKT; i += 256) {
        cd[i] = scanv[i * nb + blockIdx.x];
        cs[i] = scanv[(NBKT + i) * nb + blockIdx.x] - RE;
    }
    __syncthreads();
    int beg = blockIdx.x * CHUNK, end = min(RE, beg + CHUNK);
    for (int g = beg + (int)threadIdx.x; g < end; g += 256) {
        int rb = ((g >= E) + (g >= 2 * E)) * N;
        int s  = src[g];
        int kd = rb + dst[g];
        int pd = atomicAdd(&cd[kd >> 10], 1);
        ebd[pd] = (s << 10) | (kd & 1023);
        int ks = rb + s;
        int ps = atomicAdd(&cs[ks >> 10], 1);
        ebs[ps] = ks & 1023;
    }
}

// ---- PB: per bucket — exact histogram -> row_ptr/rs, then CSR scatter ----
__global__ __launch_bounds__(1024) void pb_kernel(const int* __restrict__ scanv, int nb, int RE,
                                                  const int* __restrict__ ebd,
                                                  const int* __restrict__ ebs,
                                                  int* __restrict__ row_ptr,
                                                  float* __restrict__ rs_in,
                                                  float* __restrict__ rs_out,
                                                  int* __restrict__ esrc) {
    __shared__ int cnt[BK];
    __shared__ int cur[BK];
    int t = threadIdx.x;
    bool dside = blockIdx.x < NBKT;
    int k = dside ? blockIdx.x : blockIdx.x - NBKT;
    int half = dside ? 0 : NBKT;
    int segbeg = scanv[(half + k) * nb];
    int segend = (k == NBKT - 1) ? (dside ? RE : 2 * RE) : scanv[(half + k + 1) * nb];
    if (!dside) { segbeg -= RE; segend -= RE; }
    cnt[t] = 0;
    __syncthreads();
    const int* __restrict__ eb = dside ? ebd : ebs;
    for (int e = segbeg + t; e < segend; e += 1024)
        atomicAdd(&cnt[eb[e] & 1023], 1);
    __syncthreads();
    int slot = k * BK + t;
    int c = cnt[t];
    if (dside) {
        cur[t] = c;
        __syncthreads();
        for (int off = 1; off < 1024; off <<= 1) {
            int u = (t >= off) ? cur[t - off] : 0;
            __syncthreads();
            cur[t] += u;
            __syncthreads();
        }
        int excl = cur[t] - c;
        if (slot < M) {
            row_ptr[slot] = segbeg + excl;
            rs_in[slot] = rsqrtf((float)(c + 1));   // +1 self-loop
        }
        if (blockIdx.x == NBKT - 1 && t == 0) row_ptr[M] = RE;
        __syncthreads();
        cur[t] = segbeg + excl;
        __syncthreads();
        for (int e = segbeg + t; e < segend; e += 1024) {
            int v = eb[e];
            int pos = atomicAdd(&cur[v & 1023], 1);
            esrc[pos] = v >> 10;
        }
    } else {
        if (slot < M) rs_out[slot] = rsqrtf((float)(c + 1));
    }
}

// ---- fp32 GEMM: Y[N,WC] = (relu?)X[N,128] @ Wr[128,WC], epilogue *= rs_out_r[row]
template <int WC, bool RELU>
__global__ __launch_bounds__(256) void gemm_kernel(const float* __restrict__ X,
                                                   const float* __restrict__ Wr,
                                                   const float* __restrict__ rs_out_r,
                                                   float* __restrict__ Y) {
    __shared__ float sX[64 * 132];
    __shared__ float sW[128 * 64];
    int tid = threadIdx.x;
    int m0  = blockIdx.x * 64;
    int c0  = blockIdx.y * 64;

    const float4* X4 = (const float4*)X;
    for (int j = tid; j < 64 * 32; j += 256) {
        int row = j >> 5, c4 = j & 31;
        float4 v = make_float4(0.f, 0.f, 0.f, 0.f);
        if (m0 + row < N) v = X4[(long)(m0 + row) * 32 + c4];
        if (RELU) {
            v.x = fmaxf(v.x, 0.f); v.y = fmaxf(v.y, 0.f);
            v.z = fmaxf(v.z, 0.f); v.w = fmaxf(v.w, 0.f);
        }
        *(float4*)&sX[row * 132 + c4 * 4] = v;
    }
    const float* Wb = Wr + c0;
    for (int j = tid; j < 128 * 16; j += 256) {
        int k = j >> 4, c4 = j & 15;
        *(float4*)&sW[k * 64 + c4 * 4] = *(const float4*)&Wb[(long)k * WC + c4 * 4];
    }
    __syncthreads();

    int tx = tid & 15;
    int ty = tid >> 4;
    float4 acc[4];
#pragma unroll
    for (int i = 0; i < 4; i++) acc[i] = make_float4(0.f, 0.f, 0.f, 0.f);

    for (int k = 0; k < 128; k += 4) {
        float4 w0 = *(float4*)&sW[(k + 0) * 64 + tx * 4];
        float4 w1 = *(float4*)&sW[(k + 1) * 64 + tx * 4];
        float4 w2 = *(float4*)&sW[(k + 2) * 64 + tx * 4];
        float4 w3 = *(float4*)&sW[(k + 3) * 64 + tx * 4];
#pragma unroll
        for (int i = 0; i < 4; i++) {
            float4 xv = *(float4*)&sX[(ty * 4 + i) * 132 + k];
            acc[i].x += xv.x * w0.x + xv.y * w1.x + xv.z * w2.x + xv.w * w3.x;
            acc[i].y += xv.x * w0.y + xv.y * w1.y + xv.z * w2.y + xv.w * w3.y;
            acc[i].z += xv.x * w0.z + xv.y * w1.z + xv.z * w2.z + xv.w * w3.z;
            acc[i].w += xv.x * w0.w + xv.y * w1.w + xv.z * w2.w + xv.w * w3.w;
        }
    }
#pragma unroll
    for (int i = 0; i < 4; i++) {
        int row = m0 + ty * 4 + i;
        if (row < N) {
            float s = rs_out_r[row];
            float4 a = acc[i];
            a.x *= s; a.y *= s; a.z *= s; a.w *= s;
            *(float4*)&Y[(long)row * WC + c0 + tx * 4] = a;
        }
    }
}

// ---- CSR aggregation, one wave per node, D=128; 4-way unrolled gathers ----
template <bool FIRST>
__global__ __launch_bounds__(256) void agg128_kernel(const float* __restrict__ Y,
                                                     const float* __restrict__ rs_in,
                                                     const int* __restrict__ row_ptr,
                                                     const int* __restrict__ esrc,
                                                     const float* __restrict__ bias,
                                                     float* __restrict__ dest, int rbase) {
    int n = blockIdx.x * 4 + (threadIdx.x >> 6);
    if (n >= N) return;
    int lane = threadIdx.x & 63;
    const float2* Y2 = (const float2*)Y;
    float px = 0.f, py = 0.f;
    int beg = row_ptr[rbase + n], end = row_ptr[rbase + n + 1];
    int e = beg;
    for (; e + 4 <= end; e += 4) {
        int s0 = esrc[e], s1 = esrc[e + 1], s2 = esrc[e + 2], s3 = esrc[e + 3];
        float2 y0 = Y2[(long)s0 * 64 + lane];
        float2 y1 = Y2[(long)s1 * 64 + lane];
        float2 y2 = Y2[(long)s2 * 64 + lane];
        float2 y3 = Y2[(long)s3 * 64 + lane];
        px += y0.x + y1.x + y2.x + y3.x;
        py += y0.y + y1.y + y2.y + y3.y;
    }
    for (; e < end; e++) {
        float2 y = Y2[(long)esrc[e] * 64 + lane];
        px += y.x; py += y.y;
    }
    { // self-loop (Y already carries rs_out)
        float2 y = Y2[(long)n * 64 + lane];
        px += y.x; py += y.y;
    }
    float ri = rs_in[rbase + n];
    float2* D2 = (float2*)dest;
    float2 d = FIRST ? ((const float2*)bias)[lane] : D2[(long)n * 64 + lane];
    d.x += ri * px; d.y += ri * py;
    D2[(long)n * 64 + lane] = d;
}

// ---- same, D=64 ----
template <bool FIRST>
__global__ __launch_bounds__(256) void agg64_kernel(const float* __restrict__ Y,
                                                    const float* __restrict__ rs_in,
                                                    const int* __restrict__ row_ptr,
                                                    const int* __restrict__ esrc,
                                                    const float* __restrict__ bias,
                                                    float* __restrict__ dest, int rbase) {
    int n = blockIdx.x * 4 + (threadIdx.x >> 6);
    if (n >= N) return;
    int lane = threadIdx.x & 63;
    float p = 0.f;
    int beg = row_ptr[rbase + n], end = row_ptr[rbase + n + 1];
    int e = beg;
    for (; e + 4 <= end; e += 4) {
        int s0 = esrc[e], s1 = esrc[e + 1], s2 = esrc[e + 2], s3 = esrc[e + 3];
        p += Y[(long)s0 * 64 + lane] + Y[(long)s1 * 64 + lane]
           + Y[(long)s2 * 64 + lane] + Y[(long)s3 * 64 + lane];
    }
    for (; e < end; e++) p += Y[(long)esrc[e] * 64 + lane];
    p += Y[(long)n * 64 + lane];
    float d = FIRST ? bias[lane] : dest[(long)n * 64 + lane];
    dest[(long)n * 64 + lane] = d + rs_in[rbase + n] * p;
}

extern "C" void kernel_launch(void* const* d_in, const int* in_sizes, int n_in,
                              void* d_out, int out_size, void* d_ws, size_t ws_size,
                              hipStream_t stream) {
    const float* x  = (const float*)d_in[0];
    const int*  src = (const int*)d_in[1];
    const int*  dst = (const int*)d_in[2];
    const float* W1 = (const float*)d_in[3];
    const float* b1 = (const float*)d_in[4];
    const float* W2 = (const float*)d_in[5];
    const float* b2 = (const float*)d_in[6];
    float* out = (float*)d_out;
    const int E  = in_sizes[1] / R;
    const int RE = in_sizes[1];
    const int nb = (RE + CHUNK - 1) / CHUNK;      // edge chunks (293)
    const int L  = 2 * NBKT * nb;                 // scan length (~86k)
    const int nb1 = (L + 1023) / 1024;            // scan1 blocks (<=256)

    char* ws = (char*)d_ws;
    size_t off = 0;
    auto alloc = [&](size_t bytes) -> void* {
        void* p = ws + off;
        off += (bytes + 255) & ~(size_t)255;
        return p;
    };
    float* bsum1    = (float*)alloc(HID * 4);
    float* bsum2    = (float*)alloc(OUT * 4);
    float* rs_in    = (float*)alloc((size_t)M * 4);
    float* rs_out   = (float*)alloc((size_t)M * 4);
    int*   row_ptr  = (int*)alloc((size_t)(M + 1) * 4);
    int*   bh       = (int*)alloc((size_t)L * 4);
    int*   scanv    = (int*)alloc((size_t)L * 4);
    int*   partials = (int*)alloc((size_t)nb1 * 4);
    int*   esrc     = (int*)alloc((size_t)RE * 4);
    // region A: ebd+ebs (19.2MB) during build, Y (25.6MB) afterwards
    char*  regA     = (char*)alloc((size_t)N * HID * 4);
    int*   ebd      = (int*)regA;
    int*   ebs      = (int*)(regA + (size_t)RE * 4);
    float* Y        = (float*)regA;
    float* H        = (float*)alloc((size_t)N * HID * 4);

    bsum_kernel<<<1, 128, 0, stream>>>(b1, b2, bsum1, bsum2);
    p1_kernel<<<nb, 256, 0, stream>>>(src, dst, E, RE, nb, bh);
    scan1_kernel<<<nb1, 1024, 0, stream>>>(bh, scanv, partials, L);
    scan2_kernel<<<1, 256, 0, stream>>>(partials, nb1);
    scan3_kernel<<<(L + 255) / 256, 256, 0, stream>>>(scanv, partials, L);
    p3_kernel<<<nb, 256, 0, stream>>>(src, dst, E, RE, nb, scanv, ebd, ebs);
    pb_kernel<<<2 * NBKT, 1024, 0, stream>>>(scanv, nb, RE, ebd, ebs,
                                             row_ptr, rs_in, rs_out, esrc);

    const int gb = (N + 63) / 64;
    const int ab = (N + 3) / 4;

    // layer 1: H = bsum1 + sum_r rs_in_r * A_sl_r * [rs_out_r * (x @ W1_r)]
    for (int r = 0; r < R; r++) {
        gemm_kernel<128, false><<<dim3(gb, 2), 256, 0, stream>>>(
            x, W1 + (size_t)r * IN * HID, rs_out + (size_t)r * N, Y);
        if (r == 0)
            agg128_kernel<true><<<ab, 256, 0, stream>>>(Y, rs_in, row_ptr, esrc, bsum1, H, r * N);
        else
            agg128_kernel<false><<<ab, 256, 0, stream>>>(Y, rs_in, row_ptr, esrc, bsum1, H, r * N);
    }
    // layer 2: out = bsum2 + sum_r rs_in_r * A_sl_r * [rs_out_r * (relu(H) @ W2_r)]
    for (int r = 0; r < R; r++) {
        gemm_kernel<64, true><<<dim3(gb, 1), 256, 0, stream>>>(
            H, W2 + (size_t)r * HID * OUT, rs_out + (size_t)r * N, Y);
        if (r == 0)
            agg64_kernel<true><<<ab, 256, 0, stream>>>(Y, rs_in, row_ptr, esrc, bsum2, out, r * N);
        else
            agg64_kernel<false><<<ab, 256, 0, stream>>>(Y, rs_in, row_ptr, esrc, bsum2, out, r * N);
    }
}